// Round 1
// baseline (478.137 us; speedup 1.0000x reference)
//
#include <hip/hip_runtime.h>
#include <cstdint>

#define B_    2
#define NQ_   768
#define NK_   768
#define DE_   256
#define DI_   256
#define DM_   32
#define FF_   128
#define DO_   64

typedef float    f32x4 __attribute__((ext_vector_type(4)));
typedef _Float16 half8 __attribute__((ext_vector_type(8)));

// ---------------------------------------------------------------------------
// Per-node precompute: one block per node (b*768+n), 128 threads.
//   e_out[node][96]  = equi @ We + be      (layout [c][m], c=0..2, m=0..31)
//   sq_out[node][32] = sum_c e[c][m]^2
//   ab_out[node][128]= (inv @ Wi + bi) @ W1[rowOff:rowOff+32] (+ b1 if addB1)
// ---------------------------------------------------------------------------
__global__ __launch_bounds__(128) void node_pre(
    const float* __restrict__ inv, const float* __restrict__ equi,
    const float* __restrict__ Wi,  const float* __restrict__ bi,
    const float* __restrict__ We,  const float* __restrict__ be,
    const float* __restrict__ W1,  int w1RowOff, int addB1,
    const float* __restrict__ b1,
    float* __restrict__ e_out, float* __restrict__ sq_out, float* __restrict__ ab_out)
{
  __shared__ float inv_s[DI_];
  __shared__ float equi_s[3*DE_];
  __shared__ float qi_s[DM_];
  __shared__ float e_s[96];
  const int node = blockIdx.x;
  const int t = threadIdx.x;
  const float* invp = inv  + (size_t)node*DI_;
  const float* eqp  = equi + (size_t)node*3*DE_;
  for (int i = t; i < DI_;   i += 128) inv_s[i]  = invp[i];
  for (int i = t; i < 3*DE_; i += 128) equi_s[i] = eqp[i];
  __syncthreads();
  if (t < 96) {
    const int c = t >> 5, m = t & 31;
    const float* eq = equi_s + c*DE_;
    float a0 = be[m], a1 = 0.f, a2 = 0.f, a3 = 0.f;
    #pragma unroll 4
    for (int d = 0; d < DE_; d += 4) {
      a0 = fmaf(eq[d+0], We[(d+0)*DM_+m], a0);
      a1 = fmaf(eq[d+1], We[(d+1)*DM_+m], a1);
      a2 = fmaf(eq[d+2], We[(d+2)*DM_+m], a2);
      a3 = fmaf(eq[d+3], We[(d+3)*DM_+m], a3);
    }
    const float acc = (a0+a1)+(a2+a3);
    e_s[t] = acc;
    e_out[(size_t)node*96 + t] = acc;
  } else {
    const int m = t & 31;
    float a0 = bi[m], a1 = 0.f, a2 = 0.f, a3 = 0.f;
    #pragma unroll 4
    for (int d = 0; d < DI_; d += 4) {
      a0 = fmaf(inv_s[d+0], Wi[(d+0)*DM_+m], a0);
      a1 = fmaf(inv_s[d+1], Wi[(d+1)*DM_+m], a1);
      a2 = fmaf(inv_s[d+2], Wi[(d+2)*DM_+m], a2);
      a3 = fmaf(inv_s[d+3], Wi[(d+3)*DM_+m], a3);
    }
    qi_s[m] = (a0+a1)+(a2+a3);
  }
  __syncthreads();
  if (t < 32) {
    const float v0 = e_s[t], v1 = e_s[32+t], v2 = e_s[64+t];
    sq_out[(size_t)node*32 + t] = v0*v0 + v1*v1 + v2*v2;
  }
  float acc = addB1 ? b1[t] : 0.f;
  #pragma unroll
  for (int m = 0; m < DM_; ++m)
    acc = fmaf(qi_s[m], W1[(w1RowOff + m)*FF_ + t], acc);
  ab_out[(size_t)node*FF_ + t] = acc;
}

// ---------------------------------------------------------------------------
// Pack W1[64:128][:] and W2 into MFMA B-fragment order (fp16).
// pk[0..8191]    : GEMM1 B, idx = ((nt*2+s)*64+lane)*8+j, nt=0..7, s=0..1
// pk[8192..16383]: GEMM2 B, idx = ((nt*4+s)*64+lane)*8+j, nt=0..3, s=0..3
// element (lane,j) of (nt,s) = W[s*32 + (lane>>4)*8 + j][nt*16 + (lane&15)]
// ---------------------------------------------------------------------------
__global__ void pack_w(const float* __restrict__ W1, const float* __restrict__ W2,
                       _Float16* __restrict__ pk)
{
  const int i = blockIdx.x*256 + threadIdx.x;   // 0..16383
  if (i < 8192) {
    const int j = i & 7, ln = (i>>3)&63, s = (i>>9)&1, nt = i>>10;
    const int row = 64 + s*32 + (ln>>4)*8 + j, col = nt*16 + (ln&15);
    pk[i] = (_Float16)W1[row*FF_ + col];
  } else {
    const int q = i - 8192;
    const int j = q & 7, ln = (q>>3)&63, s = (q>>9)&3, nt = q>>11;
    const int row = s*32 + (ln>>4)*8 + j, col = nt*16 + (ln&15);
    pk[i] = (_Float16)W2[row*DO_ + col];
  }
}

// ---------------------------------------------------------------------------
// Main pair kernel: block tile = 8 q x 16 k = 128 pairs, 4 waves.
// pair p = qL*16 + kL; M-tile t <=> qL (16 rows = kL 0..15).
// Wave split: mh = w&1 picks qL half, nh = w>>1 picks N half.
// ---------------------------------------------------------------------------
__global__ __launch_bounds__(256, 2) void pair_main(
    const float* __restrict__ qe_g, const float* __restrict__ ke_g,
    const float* __restrict__ qq_g, const float* __restrict__ kk_g,
    const float* __restrict__ Aq_g, const float* __restrict__ Bk_g,
    const _Float16* __restrict__ pk, const float* __restrict__ b2,
    float* __restrict__ out)
{
  __shared__ __align__(16) float    qe_s[8*100];   // [qL][c*32+m], pad 100
  __shared__ __align__(16) float    ke_s[16*100];
  __shared__ __align__(16) float    qq_s[8*36];
  __shared__ __align__(16) float    kk_s[16*36];
  __shared__ __align__(16) float    A_s[8*132];    // A_q (incl. b1)
  __shared__ __align__(16) float    B_s[16*132];   // B_k
  __shared__ __align__(16) _Float16 h_s[128*136];  // silu(pre), pad 136

  const int tid = threadIdx.x;
  const int b  = blockIdx.z;
  const int q0 = blockIdx.y * 8;
  const int k0 = blockIdx.x * 16;

  { const float* p = qe_g + ((size_t)b*NQ_ + q0)*96;
    for (int i = tid; i < 8*96;  i += 256) qe_s[(i/96)*100 + (i%96)] = p[i]; }
  { const float* p = ke_g + ((size_t)b*NK_ + k0)*96;
    for (int i = tid; i < 16*96; i += 256) ke_s[(i/96)*100 + (i%96)] = p[i]; }
  { const float* p = qq_g + ((size_t)b*NQ_ + q0)*32;
    for (int i = tid; i < 8*32;  i += 256) qq_s[(i>>5)*36 + (i&31)] = p[i]; }
  { const float* p = kk_g + ((size_t)b*NK_ + k0)*32;
    for (int i = tid; i < 16*32; i += 256) kk_s[(i>>5)*36 + (i&31)] = p[i]; }
  { const float* p = Aq_g + ((size_t)b*NQ_ + q0)*128;
    for (int i = tid; i < 8*128; i += 256) A_s[(i>>7)*132 + (i&127)] = p[i]; }
  { const float* p = Bk_g + ((size_t)b*NK_ + k0)*128;
    for (int i = tid; i < 16*128; i += 256) B_s[(i>>7)*132 + (i&127)] = p[i]; }
  __syncthreads();

  const int lane = tid & 63;
  const int w    = tid >> 6;
  const int mh   = w & 1;          // qL in mh*4 .. mh*4+3
  const int nh   = w >> 1;         // N half
  const int n15  = lane & 15;
  const int quad = lane >> 4;
  const int mq   = quad * 8;       // this lane's k-slot base (A-frag: k = quad*8+j)

  // GEMM1 B fragments from packed weights (L2-hot, coalesced dwordx4)
  const half8* pk1 = (const half8*)pk;
  half8 B1[4][2];
  #pragma unroll
  for (int nt = 0; nt < 4; ++nt)
    #pragma unroll
    for (int s = 0; s < 2; ++s)
      B1[nt][s] = pk1[(((nh*4+nt)*2 + s)<<6) + lane];

  f32x4 acc1[4][4];
  #pragma unroll
  for (int t = 0; t < 4; ++t)
    #pragma unroll
    for (int nt = 0; nt < 4; ++nt)
      acc1[t][nt] = (f32x4){0.f, 0.f, 0.f, 0.f};

  // k-side data for this lane's A-fragment rows (kL = n15) — hoisted
  f32x4 keF[6], kkF[2];
  #pragma unroll
  for (int c = 0; c < 3; ++c) {
    keF[c*2+0] = *(const f32x4*)&ke_s[n15*100 + c*32 + mq];
    keF[c*2+1] = *(const f32x4*)&ke_s[n15*100 + c*32 + mq + 4];
  }
  kkF[0] = *(const f32x4*)&kk_s[n15*36 + mq];
  kkF[1] = *(const f32x4*)&kk_s[n15*36 + mq + 4];

  #pragma unroll
  for (int t = 0; t < 4; ++t) {
    const int qL = mh*4 + t;
    f32x4 qeF[6], qqF[2];
    #pragma unroll
    for (int c = 0; c < 3; ++c) {
      qeF[c*2+0] = *(const f32x4*)&qe_s[qL*100 + c*32 + mq];   // broadcast
      qeF[c*2+1] = *(const f32x4*)&qe_s[qL*100 + c*32 + mq + 4];
    }
    qqF[0] = *(const f32x4*)&qq_s[qL*36 + mq];
    qqF[1] = *(const f32x4*)&qq_s[qL*36 + mq + 4];

    half8 A0, A1;
    float dots[8];
    #pragma unroll
    for (int j = 0; j < 8; ++j) {
      const int h = j >> 2, e = j & 3;
      float d = qeF[0+h][e] * keF[0+h][e];
      d = fmaf(qeF[2+h][e], keF[2+h][e], d);
      d = fmaf(qeF[4+h][e], keF[4+h][e], d);
      dots[j] = d;
      A0[j] = (_Float16)d;
    }
    #pragma unroll
    for (int j = 0; j < 8; ++j) {
      const int h = j >> 2, e = j & 3;
      float v = qqF[h][e] + kkF[h][e] - 2.f*dots[j];
      v = fmaxf(v, 0.f);                 // guard cancellation -> sqrt(neg)
      A1[j] = (_Float16)__builtin_sqrtf(v);
    }
    #pragma unroll
    for (int nt = 0; nt < 4; ++nt) {
      acc1[t][nt] = __builtin_amdgcn_mfma_f32_16x16x32_f16(A0, B1[nt][0], acc1[t][nt], 0, 0, 0);
      acc1[t][nt] = __builtin_amdgcn_mfma_f32_16x16x32_f16(A1, B1[nt][1], acc1[t][nt], 0, 0, 0);
    }
  }

  // Epilogue 1: pre = acc + A_q + B_k ; h = silu(pre) -> h_s (fp16, natural [p][f])
  #pragma unroll
  for (int nt = 0; nt < 4; ++nt) {
    const int f = ((nh*4+nt)<<4) + n15;           // C/D col: n = lane&15
    float Bv[4];
    #pragma unroll
    for (int r = 0; r < 4; ++r) Bv[r] = B_s[(quad*4+r)*132 + f];
    #pragma unroll
    for (int t = 0; t < 4; ++t) {
      const int qL = mh*4 + t;
      const float Av = A_s[qL*132 + f];
      #pragma unroll
      for (int r = 0; r < 4; ++r) {                // C/D row: m = quad*4+r = kL
        const float x = acc1[t][nt][r] + Av + Bv[r];
        const float sg = __builtin_amdgcn_rcpf(1.f + __expf(-x));
        h_s[(qL*16 + quad*4 + r)*136 + f] = (_Float16)(x * sg);
      }
    }
  }
  __syncthreads();

  // GEMM2: out = h @ W2, K = 128 (4 steps), N = 64 (wave covers 2 n-tiles)
  const half8* pk2 = (const half8*)(pk + 8192);
  half8 B2[2][4];
  #pragma unroll
  for (int nt = 0; nt < 2; ++nt)
    #pragma unroll
    for (int s = 0; s < 4; ++s)
      B2[nt][s] = pk2[(((nh*2+nt)*4 + s)<<6) + lane];

  f32x4 acc2[4][2];
  #pragma unroll
  for (int t = 0; t < 4; ++t) { acc2[t][0] = (f32x4){0.f,0.f,0.f,0.f};
                                acc2[t][1] = (f32x4){0.f,0.f,0.f,0.f}; }
  #pragma unroll
  for (int t = 0; t < 4; ++t) {
    const int qL = mh*4 + t;
    #pragma unroll
    for (int s = 0; s < 4; ++s) {
      const half8 A2 = *(const half8*)&h_s[(qL*16 + n15)*136 + s*32 + mq];
      acc2[t][0] = __builtin_amdgcn_mfma_f32_16x16x32_f16(A2, B2[0][s], acc2[t][0], 0, 0, 0);
      acc2[t][1] = __builtin_amdgcn_mfma_f32_16x16x32_f16(A2, B2[1][s], acc2[t][1], 0, 0, 0);
    }
  }

  // Epilogue 2: + b2, store (16 lanes -> 64B contiguous per o-group)
  #pragma unroll
  for (int nt = 0; nt < 2; ++nt) {
    const int o = ((nh*2+nt)<<4) + n15;
    const float bias = b2[o];
    #pragma unroll
    for (int t = 0; t < 4; ++t) {
      const int q = q0 + mh*4 + t;
      float* op = out + (((size_t)b*NQ_ + q)*NK_ + k0 + quad*4)*DO_ + o;
      #pragma unroll
      for (int r = 0; r < 4; ++r)
        op[(size_t)r*DO_] = acc2[t][nt][r] + bias;
    }
  }
}

extern "C" void kernel_launch(void* const* d_in, const int* in_sizes, int n_in,
                              void* d_out, int out_size, void* d_ws, size_t ws_size,
                              hipStream_t stream) {
  const float* q_equi = (const float*)d_in[0];
  const float* q_inv  = (const float*)d_in[1];
  const float* k_equi = (const float*)d_in[2];
  const float* k_inv  = (const float*)d_in[3];
  const float* Wqi = (const float*)d_in[4];
  const float* bqi = (const float*)d_in[5];
  const float* Wki = (const float*)d_in[6];
  const float* bki = (const float*)d_in[7];
  const float* Wqe = (const float*)d_in[8];
  const float* bqe = (const float*)d_in[9];
  const float* Wke = (const float*)d_in[10];
  const float* bke = (const float*)d_in[11];
  const float* W1  = (const float*)d_in[12];
  const float* b1  = (const float*)d_in[13];
  const float* W2  = (const float*)d_in[14];
  const float* b2  = (const float*)d_in[15];

  float* ws = (float*)d_ws;                 // ~3.2 MB of scratch used
  float* qe = ws;                           // [B*NQ][96]
  float* ke = qe + (size_t)B_*NQ_*96;       // [B*NK][96]
  float* qq = ke + (size_t)B_*NK_*96;       // [B*NQ][32]
  float* kk = qq + (size_t)B_*NQ_*32;       // [B*NK][32]
  float* Aq = kk + (size_t)B_*NK_*32;       // [B*NQ][128]
  float* Bk = Aq + (size_t)B_*NQ_*128;      // [B*NK][128]
  _Float16* pk = (_Float16*)(Bk + (size_t)B_*NK_*128);  // 16384 fp16

  node_pre<<<B_*NQ_, 128, 0, stream>>>(q_inv, q_equi, Wqi, bqi, Wqe, bqe, W1, 0, 1, b1, qe, qq, Aq);
  node_pre<<<B_*NK_, 128, 0, stream>>>(k_inv, k_equi, Wki, bki, Wke, bke, W1, 32, 0, b1, ke, kk, Bk);
  pack_w<<<64, 256, 0, stream>>>(W1, W2, pk);

  dim3 grid(NK_/16, NQ_/8, B_);
  pair_main<<<grid, 256, 0, stream>>>(qe, ke, qq, kk, Aq, Bk, pk, b2, (float*)d_out);
}

// Round 2
// 465.387 us; speedup vs baseline: 1.0274x; 1.0274x over previous
//
#include <hip/hip_runtime.h>
#include <cstdint>

#define B_    2
#define NQ_   768
#define NK_   768
#define DE_   256
#define DI_   256
#define DM_   32
#define FF_   128
#define DO_   64

typedef float    f32x4 __attribute__((ext_vector_type(4)));
typedef _Float16 half8 __attribute__((ext_vector_type(8)));

// ---------------------------------------------------------------------------
// Merged per-node precompute (+ weight packing in the extra grid column).
// grid = (B*768 + 1, 2); blockIdx.y = 0 -> q side, 1 -> k side.
//   e_out[node][96]  = equi @ We + be      (layout [c][m])
//   sq_out[node][32] = sum_c e[c][m]^2
//   ab_out[node][128]= (inv @ Wi + bi) @ W1[rowOff:rowOff+32] (+ b1 on q side)
// pack (x == B*768): W1[64:128]/W2 -> MFMA B-fragment order, fp16.
// ---------------------------------------------------------------------------
__global__ __launch_bounds__(128) void node_pre_all(
    const float* __restrict__ q_inv, const float* __restrict__ q_equi,
    const float* __restrict__ k_inv, const float* __restrict__ k_equi,
    const float* __restrict__ Wqi, const float* __restrict__ bqi,
    const float* __restrict__ Wki, const float* __restrict__ bki,
    const float* __restrict__ Wqe, const float* __restrict__ bqe,
    const float* __restrict__ Wke, const float* __restrict__ bke,
    const float* __restrict__ W1,  const float* __restrict__ b1,
    const float* __restrict__ W2,
    float* __restrict__ qe, float* __restrict__ qq, float* __restrict__ Aq,
    float* __restrict__ ke, float* __restrict__ kk, float* __restrict__ Bk,
    _Float16* __restrict__ pk)
{
  const int side = blockIdx.y;
  const int t = threadIdx.x;

  if (blockIdx.x == B_*NQ_) {          // ---- weight-pack blocks ----
    if (side == 0) {
      for (int i = t; i < 8192; i += 128) {
        const int j = i & 7, ln = (i>>3)&63, s = (i>>9)&1, nt = i>>10;
        const int row = 64 + s*32 + (ln>>4)*8 + j, col = nt*16 + (ln&15);
        pk[i] = (_Float16)W1[row*FF_ + col];
      }
    } else {
      for (int i = t; i < 8192; i += 128) {
        const int j = i & 7, ln = (i>>3)&63, s = (i>>9)&3, nt = i>>11;
        const int row = s*32 + (ln>>4)*8 + j, col = nt*16 + (ln&15);
        pk[8192 + i] = (_Float16)W2[row*DO_ + col];
      }
    }
    return;
  }

  const float* inv  = side ? k_inv  : q_inv;
  const float* equi = side ? k_equi : q_equi;
  const float* Wi   = side ? Wki : Wqi;
  const float* bi   = side ? bki : bqi;
  const float* We   = side ? Wke : Wqe;
  const float* be   = side ? bke : bqe;
  const int w1RowOff = side ? 32 : 0;
  const int addB1    = side ? 0 : 1;
  float* e_out  = side ? ke : qe;
  float* sq_out = side ? kk : qq;
  float* ab_out = side ? Bk : Aq;

  __shared__ float inv_s[DI_];
  __shared__ float equi_s[3*DE_];
  __shared__ float qi_s[DM_];
  __shared__ float e_s[96];
  const int node = blockIdx.x;
  const float* invp = inv  + (size_t)node*DI_;
  const float* eqp  = equi + (size_t)node*3*DE_;
  for (int i = t; i < DI_;   i += 128) inv_s[i]  = invp[i];
  for (int i = t; i < 3*DE_; i += 128) equi_s[i] = eqp[i];
  __syncthreads();
  if (t < 96) {
    const int c = t >> 5, m = t & 31;
    const float* eq = equi_s + c*DE_;
    float a0 = be[m], a1 = 0.f, a2 = 0.f, a3 = 0.f;
    #pragma unroll 4
    for (int d = 0; d < DE_; d += 4) {
      a0 = fmaf(eq[d+0], We[(d+0)*DM_+m], a0);
      a1 = fmaf(eq[d+1], We[(d+1)*DM_+m], a1);
      a2 = fmaf(eq[d+2], We[(d+2)*DM_+m], a2);
      a3 = fmaf(eq[d+3], We[(d+3)*DM_+m], a3);
    }
    const float acc = (a0+a1)+(a2+a3);
    e_s[t] = acc;
    e_out[(size_t)node*96 + t] = acc;
  } else {
    const int m = t & 31;
    float a0 = bi[m], a1 = 0.f, a2 = 0.f, a3 = 0.f;
    #pragma unroll 4
    for (int d = 0; d < DI_; d += 4) {
      a0 = fmaf(inv_s[d+0], Wi[(d+0)*DM_+m], a0);
      a1 = fmaf(inv_s[d+1], Wi[(d+1)*DM_+m], a1);
      a2 = fmaf(inv_s[d+2], Wi[(d+2)*DM_+m], a2);
      a3 = fmaf(inv_s[d+3], Wi[(d+3)*DM_+m], a3);
    }
    qi_s[m] = (a0+a1)+(a2+a3);
  }
  __syncthreads();
  if (t < 32) {
    const float v0 = e_s[t], v1 = e_s[32+t], v2 = e_s[64+t];
    sq_out[(size_t)node*32 + t] = v0*v0 + v1*v1 + v2*v2;
  }
  float acc = addB1 ? b1[t] : 0.f;
  #pragma unroll
  for (int m = 0; m < DM_; ++m)
    acc = fmaf(qi_s[m], W1[(w1RowOff + m)*FF_ + t], acc);
  ab_out[(size_t)node*FF_ + t] = acc;
}

// ---------------------------------------------------------------------------
// Main pair kernel: block tile = 8 q x 16 k = 128 pairs, 4 waves.
// pair p = qL*16 + kL. Wave w owns qL in {2w, 2w+1} and the FULL N range
// (no duplicated dot/dist work; h/o tile rows are wave-private -> fewer
// barriers). Epilogue 2 transposes through LDS for coalesced float4 stores.
// ---------------------------------------------------------------------------
__global__ __launch_bounds__(256, 2) void pair_main(
    const float* __restrict__ qe_g, const float* __restrict__ ke_g,
    const float* __restrict__ qq_g, const float* __restrict__ kk_g,
    const float* __restrict__ Aq_g, const float* __restrict__ Bk_g,
    const _Float16* __restrict__ pk, const float* __restrict__ b2,
    float* __restrict__ out)
{
  __shared__ __align__(16) float qe_s[8*100];    // [qL][c*32+m], pad 100
  __shared__ __align__(16) float ke_s[16*100];
  __shared__ __align__(16) float qq_s[8*36];
  __shared__ __align__(16) float kk_s[16*36];
  __shared__ __align__(16) float A_s[8*132];     // A_q (incl. b1)
  __shared__ __align__(16) float B_s[16*132];    // B_k
  // h (fp16, [128][136]) and o (f32, [128][68]) alias: both 34816 B,
  // both 272 B per pair-row; rows are wave-private so reuse is race-free.
  __shared__ __align__(16) unsigned char hs_raw[128*136*2];
  _Float16* h_s = (_Float16*)hs_raw;
  float*    o_s = (float*)hs_raw;

  const int tid = threadIdx.x;
  const int b  = blockIdx.z;
  const int q0 = blockIdx.y * 8;
  const int k0 = blockIdx.x * 16;

  { const float* p = qe_g + ((size_t)b*NQ_ + q0)*96;
    for (int i = tid; i < 8*96;  i += 256) qe_s[(i/96)*100 + (i%96)] = p[i]; }
  { const float* p = ke_g + ((size_t)b*NK_ + k0)*96;
    for (int i = tid; i < 16*96; i += 256) ke_s[(i/96)*100 + (i%96)] = p[i]; }
  { const float* p = qq_g + ((size_t)b*NQ_ + q0)*32;
    for (int i = tid; i < 8*32;  i += 256) qq_s[(i>>5)*36 + (i&31)] = p[i]; }
  { const float* p = kk_g + ((size_t)b*NK_ + k0)*32;
    for (int i = tid; i < 16*32; i += 256) kk_s[(i>>5)*36 + (i&31)] = p[i]; }
  { const float* p = Aq_g + ((size_t)b*NQ_ + q0)*128;
    for (int i = tid; i < 8*128; i += 256) A_s[(i>>7)*132 + (i&127)] = p[i]; }
  { const float* p = Bk_g + ((size_t)b*NK_ + k0)*128;
    for (int i = tid; i < 16*128; i += 256) B_s[(i>>7)*132 + (i&127)] = p[i]; }
  __syncthreads();

  const int lane = tid & 63;
  const int w    = tid >> 6;       // wave owns qL = 2w, 2w+1
  const int n15  = lane & 15;
  const int quad = lane >> 4;
  const int mq   = quad * 8;       // A-frag: k = quad*8 + j

  // GEMM1 B fragments (all 8 n-tiles x 2 k-steps), L2-hot dwordx4
  const half8* pk1 = (const half8*)pk;
  half8 B1[8][2];
  #pragma unroll
  for (int nt = 0; nt < 8; ++nt)
    #pragma unroll
    for (int s = 0; s < 2; ++s)
      B1[nt][s] = pk1[((nt*2 + s)<<6) + lane];

  f32x4 acc1[2][8];
  #pragma unroll
  for (int t = 0; t < 2; ++t)
    #pragma unroll
    for (int nt = 0; nt < 8; ++nt)
      acc1[t][nt] = (f32x4){0.f, 0.f, 0.f, 0.f};

  // k-side fragment rows (kL = n15), hoisted
  f32x4 keF[6], kkF[2];
  #pragma unroll
  for (int c = 0; c < 3; ++c) {
    keF[c*2+0] = *(const f32x4*)&ke_s[n15*100 + c*32 + mq];
    keF[c*2+1] = *(const f32x4*)&ke_s[n15*100 + c*32 + mq + 4];
  }
  kkF[0] = *(const f32x4*)&kk_s[n15*36 + mq];
  kkF[1] = *(const f32x4*)&kk_s[n15*36 + mq + 4];

  #pragma unroll
  for (int t = 0; t < 2; ++t) {
    const int qL = 2*w + t;
    f32x4 qeF[6], qqF[2];
    #pragma unroll
    for (int c = 0; c < 3; ++c) {
      qeF[c*2+0] = *(const f32x4*)&qe_s[qL*100 + c*32 + mq];   // broadcast
      qeF[c*2+1] = *(const f32x4*)&qe_s[qL*100 + c*32 + mq + 4];
    }
    qqF[0] = *(const f32x4*)&qq_s[qL*36 + mq];
    qqF[1] = *(const f32x4*)&qq_s[qL*36 + mq + 4];

    half8 A0, A1;
    float dots[8];
    #pragma unroll
    for (int j = 0; j < 8; ++j) {
      const int h = j >> 2, e = j & 3;
      float d = qeF[0+h][e] * keF[0+h][e];
      d = fmaf(qeF[2+h][e], keF[2+h][e], d);
      d = fmaf(qeF[4+h][e], keF[4+h][e], d);
      dots[j] = d;
      A0[j] = (_Float16)d;
    }
    #pragma unroll
    for (int j = 0; j < 8; ++j) {
      const int h = j >> 2, e = j & 3;
      float v = qqF[h][e] + kkF[h][e] - 2.f*dots[j];
      v = fmaxf(v, 0.f);
      A1[j] = (_Float16)__builtin_sqrtf(v);
    }
    #pragma unroll
    for (int nt = 0; nt < 8; ++nt) {
      acc1[t][nt] = __builtin_amdgcn_mfma_f32_16x16x32_f16(A0, B1[nt][0], acc1[t][nt], 0, 0, 0);
      acc1[t][nt] = __builtin_amdgcn_mfma_f32_16x16x32_f16(A1, B1[nt][1], acc1[t][nt], 0, 0, 0);
    }
  }

  // Epilogue 1: pre = acc + A_q + B_k ; h = silu(pre) -> h_s (wave-private rows)
  #pragma unroll
  for (int nt = 0; nt < 8; ++nt) {
    const int f = (nt<<4) + n15;                  // C/D col
    float Bv[4];
    #pragma unroll
    for (int r = 0; r < 4; ++r) Bv[r] = B_s[(quad*4+r)*132 + f];
    #pragma unroll
    for (int t = 0; t < 2; ++t) {
      const int qL = 2*w + t;
      const float Av = A_s[qL*132 + f];
      #pragma unroll
      for (int r = 0; r < 4; ++r) {               // C/D row = kL
        const float x = acc1[t][nt][r] + Av + Bv[r];
        const float e = __builtin_amdgcn_exp2f(-1.44269504f * x);
        h_s[(qL*16 + quad*4 + r)*136 + f] = (_Float16)(x * __builtin_amdgcn_rcpf(1.f + e));
      }
    }
  }
  // no barrier: each wave reads only the h rows it just wrote

  // GEMM2: out = h @ W2, K = 128 (4 steps), N = 64 (4 n-tiles)
  const half8* pk2 = (const half8*)(pk + 8192);
  half8 B2[4][4];
  #pragma unroll
  for (int nt = 0; nt < 4; ++nt)
    #pragma unroll
    for (int s = 0; s < 4; ++s)
      B2[nt][s] = pk2[((nt*4 + s)<<6) + lane];

  f32x4 acc2[2][4];
  #pragma unroll
  for (int t = 0; t < 2; ++t)
    #pragma unroll
    for (int nt = 0; nt < 4; ++nt)
      acc2[t][nt] = (f32x4){0.f,0.f,0.f,0.f};

  #pragma unroll
  for (int t = 0; t < 2; ++t) {
    const int qL = 2*w + t;
    #pragma unroll
    for (int s = 0; s < 4; ++s) {
      const half8 A2 = *(const half8*)&h_s[(qL*16 + n15)*136 + s*32 + mq];
      #pragma unroll
      for (int nt = 0; nt < 4; ++nt)
        acc2[t][nt] = __builtin_amdgcn_mfma_f32_16x16x32_f16(A2, B2[nt][s], acc2[t][nt], 0, 0, 0);
    }
  }

  // Epilogue 2a: + b2, transpose into o_s (aliases h_s; rows wave-private,
  // and this wave's h rows are fully consumed above)
  float bias[4];
  #pragma unroll
  for (int nt = 0; nt < 4; ++nt) bias[nt] = b2[(nt<<4) + n15];
  #pragma unroll
  for (int nt = 0; nt < 4; ++nt) {
    const int o = (nt<<4) + n15;
    #pragma unroll
    for (int t = 0; t < 2; ++t) {
      const int qL = 2*w + t;
      #pragma unroll
      for (int r = 0; r < 4; ++r)
        o_s[(qL*16 + quad*4 + r)*68 + o] = acc2[t][nt][r] + bias[nt];
    }
  }
  __syncthreads();

  // Epilogue 2b: coalesced float4 stores (1 KB per wave per instruction)
  const size_t outBase = (((size_t)b*NQ_ + q0)*NK_ + k0)*DO_;
  #pragma unroll
  for (int c = 0; c < 8; ++c) {
    const int idx  = c*256 + tid;        // 0..2047 float4 chunks
    const int pair = idx >> 4;
    const int o4   = (idx & 15) << 2;
    const int qL   = pair >> 4;
    const int kL   = pair & 15;
    const f32x4 v = *(const f32x4*)&o_s[pair*68 + o4];
    *(f32x4*)&out[outBase + ((size_t)qL*NK_ + kL)*DO_ + o4] = v;
  }
}

extern "C" void kernel_launch(void* const* d_in, const int* in_sizes, int n_in,
                              void* d_out, int out_size, void* d_ws, size_t ws_size,
                              hipStream_t stream) {
  const float* q_equi = (const float*)d_in[0];
  const float* q_inv  = (const float*)d_in[1];
  const float* k_equi = (const float*)d_in[2];
  const float* k_inv  = (const float*)d_in[3];
  const float* Wqi = (const float*)d_in[4];
  const float* bqi = (const float*)d_in[5];
  const float* Wki = (const float*)d_in[6];
  const float* bki = (const float*)d_in[7];
  const float* Wqe = (const float*)d_in[8];
  const float* bqe = (const float*)d_in[9];
  const float* Wke = (const float*)d_in[10];
  const float* bke = (const float*)d_in[11];
  const float* W1  = (const float*)d_in[12];
  const float* b1  = (const float*)d_in[13];
  const float* W2  = (const float*)d_in[14];
  const float* b2  = (const float*)d_in[15];

  float* ws = (float*)d_ws;
  float* qe = ws;                           // [B*NQ][96]
  float* ke = qe + (size_t)B_*NQ_*96;       // [B*NK][96]
  float* qq = ke + (size_t)B_*NK_*96;       // [B*NQ][32]
  float* kk = qq + (size_t)B_*NQ_*32;       // [B*NK][32]
  float* Aq = kk + (size_t)B_*NK_*32;       // [B*NQ][128]
  float* Bk = Aq + (size_t)B_*NQ_*128;      // [B*NK][128]
  _Float16* pk = (_Float16*)(Bk + (size_t)B_*NK_*128);  // 16384 fp16

  dim3 ngrid(B_*NQ_ + 1, 2);
  node_pre_all<<<ngrid, 128, 0, stream>>>(
      q_inv, q_equi, k_inv, k_equi, Wqi, bqi, Wki, bki, Wqe, bqe, Wke, bke,
      W1, b1, W2, qe, qq, Aq, ke, kk, Bk, pk);

  dim3 grid(NK_/16, NQ_/8, B_);
  pair_main<<<grid, 256, 0, stream>>>(qe, ke, qq, kk, Aq, Bk, pk, b2, (float*)d_out);
}